// Round 1
// baseline (27.093 us; speedup 1.0000x reference)
//
#include <hip/hip_runtime.h>
#include <math.h>

#define NA 512
#define NQC 8
#define SRC_STRIDE 12   // floats per (i,q) packed record (3 x float4)

#define NCf ((float)(90.4756 / 6.28318530717958647692))
#define A_ERF 0.70710678118654752f      // 1/sqrt(2)
#define G_COEF 0.79788456080286536f     // sqrt(2/pi)

// ---------------- pack kernel: per-(i,q) moments + r as float4 ----------------
__global__ void pack_kernel(const float* __restrict__ q,
                            const float* __restrict__ r,
                            const float* __restrict__ u,
                            const float* __restrict__ quad,
                            float* __restrict__ ws_src,
                            float4* __restrict__ ws_r4) {
    int idx = blockIdx.x * blockDim.x + threadIdx.x;   // 0..4095
    if (idx < NA) {
        ws_r4[idx] = make_float4(r[idx*3+0], r[idx*3+1], r[idx*3+2], 0.0f);
    }
    if (idx >= NA * NQC) return;
    const float* Q = quad + (size_t)idx * 9;
    float xx = Q[0], yy = Q[4], zz = Q[8];
    float xy = 0.5f * (Q[1] + Q[3]);
    float xz = 0.5f * (Q[2] + Q[6]);
    float yz = 0.5f * (Q[5] + Q[7]);
    float tq = xx + yy + zz;
    float* s = ws_src + (size_t)idx * SRC_STRIDE;
    s[0]  = q[idx];
    s[1]  = tq;
    s[2]  = u[idx*3+0];
    s[3]  = u[idx*3+1];
    s[4]  = u[idx*3+2];
    s[5]  = xx; s[6] = yy; s[7] = zz;
    s[8]  = xy; s[9] = xz; s[10] = yz;
    s[11] = 0.0f;
}

// ---------------- main kernel ----------------
// block = 256 threads: q = tid&7 (channel), seg = tid>>3 (i-segment of 16)
// grid = 512 blocks: one receiver j per block
template<bool PACKED>
__global__ __launch_bounds__(256)
void main_kernel(const float* __restrict__ ws_src,
                 const float4* __restrict__ r4,
                 const float* __restrict__ rraw,
                 const float* __restrict__ qarr,
                 const float* __restrict__ uarr,
                 const float* __restrict__ quadarr,
                 const float* __restrict__ kaparr,
                 const float* __restrict__ alparr,
                 float* __restrict__ out,
                 float* __restrict__ potpart) {
    const int j   = blockIdx.x;
    const int tid = threadIdx.x;
    const int qch = tid & 7;
    const int seg = tid >> 3;   // 0..31

    // receiver position
    float rjx, rjy, rjz;
    if (PACKED) {
        float4 rj = r4[j];
        rjx = rj.x; rjy = rj.y; rjz = rj.z;
    } else {
        rjx = rraw[j*3+0]; rjy = rraw[j*3+1]; rjz = rraw[j*3+2];
    }

    // receiver symmetric quadrupole (per-channel) held across the loop
    const int jq = j * NQC + qch;
    float jxx, jyy, jzz, jxy, jxz, jyz, jtq;
    if (PACKED) {
        const float* sj = ws_src + (size_t)jq * SRC_STRIDE;
        jtq = sj[1]; jxx = sj[5]; jyy = sj[6]; jzz = sj[7];
        jxy = sj[8]; jxz = sj[9]; jyz = sj[10];
    } else {
        const float* Q = quadarr + (size_t)jq * 9;
        jxx = Q[0]; jyy = Q[4]; jzz = Q[8];
        jxy = 0.5f*(Q[1]+Q[3]); jxz = 0.5f*(Q[2]+Q[6]); jyz = 0.5f*(Q[5]+Q[7]);
        jtq = jxx + jyy + jzz;
    }

    float e0 = 0.f, eph = 0.f;
    float Fx = 0.f, Fy = 0.f, Fz = 0.f;
    float Hx = 0.f, Hy = 0.f, Hz = 0.f;
    float pQQ = 0.f;

    #pragma unroll 4
    for (int k = 0; k < 16; ++k) {
        const int i = seg * 16 + k;
        float dx, dy, dz;
        if (PACKED) {
            float4 ri = r4[i];
            dx = rjx - ri.x; dy = rjy - ri.y; dz = rjz - ri.z;
        } else {
            dx = rjx - rraw[i*3+0]; dy = rjy - rraw[i*3+1]; dz = rjz - rraw[i*3+2];
        }
        float r2 = dx*dx + dy*dy + dz*dz;
        const bool diag = (i == j);
        if (diag) r2 = 1.0f;
        const float ir  = rsqrtf(r2);
        const float rr  = r2 * ir;
        const float E   = erff(A_ERF * rr);
        const float G   = G_COEF * __expf(-0.5f * r2);
        const float ir2 = ir * ir;
        const float ir4 = ir2 * ir2;
        const float g   = E * ir;
        const float GmG = G - g;               // (G - E/r)
        const float nco = diag ? 0.0f : NCf;
        const float c0 = nco * g;
        const float c1 = nco * ir2 * GmG;
        const float c2 = nco * ir2 * (-3.0f*ir2*GmG - G);
        const float c3 = nco * ir2 * (15.0f*ir4*GmG + 5.0f*G*ir2 + G);
        const float c4 = nco * ir2 * (-105.0f*ir4*ir2*GmG - 35.0f*G*ir4 - 7.0f*G*ir2 - G);

        // per-channel source moments
        float qi, tqi, ux, uy, uz, xx, yy, zz, xy, xz, yz;
        if (PACKED) {
            const float4* s4 = (const float4*)(ws_src + (size_t)(i*NQC + qch) * SRC_STRIDE);
            float4 sa = s4[0], sb = s4[1], sc = s4[2];
            qi = sa.x; tqi = sa.y; ux = sa.z; uy = sa.w;
            uz = sb.x; xx = sb.y; yy = sb.z; zz = sb.w;
            xy = sc.x; xz = sc.y; yz = sc.z;
        } else {
            const int iq = i*NQC + qch;
            qi = qarr[iq];
            ux = uarr[iq*3+0]; uy = uarr[iq*3+1]; uz = uarr[iq*3+2];
            const float* Q = quadarr + (size_t)iq * 9;
            xx = Q[0]; yy = Q[4]; zz = Q[8];
            xy = 0.5f*(Q[1]+Q[3]); xz = 0.5f*(Q[2]+Q[6]); yz = 0.5f*(Q[5]+Q[7]);
            tqi = xx + yy + zz;
        }

        const float ud  = ux*dx + uy*dy + uz*dz;
        const float Pdx = xx*dx + xy*dy + xz*dz;
        const float Pdy = xy*dx + yy*dy + yz*dz;
        const float Pdz = xz*dx + yz*dy + zz*dz;
        const float Pdd = Pdx*dx + Pdy*dy + Pdz*dz;

        const float t0 = c0 * qi;
        e0  += t0;
        eph += t0 - c1*ud + 0.5f*(c2*Pdd + c1*tqi);

        const float cH = 0.5f*(c2*(ud - tqi) - c3*Pdd);
        const float cF = cH + 0.5f*c2*ud - c1*qi;
        const float c1h = 0.5f * c1;
        Fx += cF*dx + c1*ux - c2*Pdx;
        Fy += cF*dy + c1*uy - c2*Pdy;
        Fz += cF*dz + c1*uz - c2*Pdz;
        Hx += cH*dx + c1h*ux - c2*Pdx;
        Hy += cH*dy + c1h*uy - c2*Pdy;
        Hz += cH*dz + c1h*uz - c2*Pdz;

        // quad_j : QQ contribution (scalar)
        const float Rdx = jxx*dx + jxy*dy + jxz*dz;
        const float Rdy = jxy*dx + jyy*dy + jyz*dz;
        const float Rdz = jxz*dx + jyz*dy + jzz*dz;
        const float Rdd = Rdx*dx + Rdy*dy + Rdz*dz;
        const float dPR = Pdx*Rdx + Pdy*Rdy + Pdz*Rdz;
        const float frob = xx*jxx + yy*jyy + zz*jzz + 2.0f*(xy*jxy + xz*jxz + yz*jyz);
        pQQ += c4*(Pdd*Rdd)
             + c3*(jtq*Pdd + tqi*Rdd + 4.0f*dPR)
             + c2*(tqi*jtq + 2.0f*frob);
    }

    // ---- reduction over segments ----
    float acc[9] = {e0, eph, Fx, Fy, Fz, Hx, Hy, Hz, pQQ};
    #pragma unroll
    for (int off = 8; off < 64; off <<= 1) {
        #pragma unroll
        for (int c = 0; c < 9; ++c) acc[c] += __shfl_xor(acc[c], off, 64);
    }
    __shared__ float lds[4][8][9];
    const int lane = tid & 63, wv = tid >> 6;
    if ((lane & 56) == 0) {
        #pragma unroll
        for (int c = 0; c < 9; ++c) lds[wv][lane][c] = acc[c];
    }
    __syncthreads();
    if (tid < 8) {
        float v[9];
        #pragma unroll
        for (int c = 0; c < 9; ++c)
            v[c] = lds[0][tid][c] + lds[1][tid][c] + lds[2][tid][c] + lds[3][tid][c];
        const float te0 = v[0], teph = v[1];
        const float tFx = v[2], tFy = v[3], tFz = v[4];
        const float tHx = v[5], tHy = v[6], tHz = v[7];
        const float tQQ = v[8] * 0.125f;
        const int myjq = j * NQC + tid;
        const float qj  = qarr[myjq];
        const float ujx = uarr[myjq*3+0], ujy = uarr[myjq*3+1], ujz = uarr[myjq*3+2];
        const float kapv = kaparr[myjq];
        const float alpv = alparr[myjq];

        float pot = qj * (teph - 0.5f*te0)
                  - (ujx*tHx + ujy*tHy + ujz*tHz)
                  + tQQ
                  - 0.5f * kapv * teph * teph
                  - 0.5f * alpv * (tFx*tFx + tFy*tFy + tFz*tFz);

        out[1 + myjq] = -kapv * teph;
        out[1 + NA*NQC + myjq*3 + 0] = alpv * tFx;
        out[1 + NA*NQC + myjq*3 + 1] = alpv * tFy;
        out[1 + NA*NQC + myjq*3 + 2] = alpv * tFz;

        #pragma unroll
        for (int off = 4; off; off >>= 1) pot += __shfl_xor(pot, off, 8);
        if (tid == 0) potpart[j] = pot;
    }
}

// ---------------- pot reduction ----------------
__global__ void pot_kernel(const float* __restrict__ potpart, float* __restrict__ out) {
    const int tid = threadIdx.x;    // 512 threads, 1 block
    float p = potpart[tid];
    #pragma unroll
    for (int off = 32; off; off >>= 1) p += __shfl_xor(p, off, 64);
    __shared__ float l[8];
    if ((tid & 63) == 0) l[tid >> 6] = p;
    __syncthreads();
    if (tid == 0) {
        float s = 0.f;
        #pragma unroll
        for (int w = 0; w < 8; ++w) s += l[w];
        out[0] = s;
    }
}

extern "C" void kernel_launch(void* const* d_in, const int* in_sizes, int n_in,
                              void* d_out, int out_size, void* d_ws, size_t ws_size,
                              hipStream_t stream) {
    const float* q    = (const float*)d_in[0];
    const float* r    = (const float*)d_in[1];
    const float* u    = (const float*)d_in[4];
    const float* quad = (const float*)d_in[5];
    const float* kap  = (const float*)d_in[6];
    const float* alp  = (const float*)d_in[7];
    float* out = (float*)d_out;
    float* ws  = (float*)d_ws;

    const size_t src_floats = (size_t)NA * NQC * SRC_STRIDE;            // 49152
    const size_t needed = src_floats*4 + (size_t)NA*16 + (size_t)NA*4;  // ~207 KB

    if (ws_size >= needed) {
        float*  ws_src  = ws;
        float4* r4      = (float4*)(ws + src_floats);
        float*  potpart = (float*)(r4 + NA);
        pack_kernel<<<16, 256, 0, stream>>>(q, r, u, quad, ws_src, r4);
        main_kernel<true><<<NA, 256, 0, stream>>>(ws_src, r4, r, q, u, quad, kap, alp, out, potpart);
        pot_kernel<<<1, 512, 0, stream>>>(potpart, out);
    } else {
        float* potpart = ws;   // needs only 2 KB
        main_kernel<false><<<NA, 256, 0, stream>>>(nullptr, nullptr, r, q, u, quad, kap, alp, out, potpart);
        pot_kernel<<<1, 512, 0, stream>>>(potpart, out);
    }
}